// Round 4
// baseline (1657.081 us; speedup 1.0000x reference)
//
#include <hip/hip_runtime.h>
#include <hip/hip_bf16.h>
#include <math.h>

#define NB 8
#define NH 12
#define SEQ 784
#define CH 768
#define DH 64
#define K_TOP 100
#define NE4 196   // SEQ/4

typedef long long i64;
typedef __attribute__((ext_vector_type(8))) short bf16x8;
typedef __attribute__((ext_vector_type(4))) float f32x4;

// ---------------- QKV GEMM: C = A @ B^T, fp32 vector, BK=16, padded LDS ----
__global__ __launch_bounds__(256)
void gemm_qkv(const float* __restrict__ A, const float* __restrict__ B,
              float* __restrict__ C)
{
    __shared__ __align__(16) float As[16][132];   // +4 pad: store conflicts 4->2 way
    __shared__ __align__(16) float Bs[16][132];
    const int tid = threadIdx.x;
    const int tx = tid & 15, ty = tid >> 4;
    const int m0 = blockIdx.y * 128, n0 = blockIdx.x * 128;

    const int r  = tid >> 2;          // 0..63
    const int kc = (tid & 3) << 2;    // 0,4,8,12
    const float* ApL = A + (i64)(m0 + r)      * CH + kc;
    const float* ApH = A + (i64)(m0 + r + 64) * CH + kc;
    const float* BpL = B + (i64)(n0 + r)      * CH + kc;
    const float* BpH = B + (i64)(n0 + r + 64) * CH + kc;

    float4 a0 = *(const float4*)ApL, a1 = *(const float4*)ApH;
    float4 b0 = *(const float4*)BpL, b1 = *(const float4*)BpH;

    float acc[8][8];
#pragma unroll
    for (int i = 0; i < 8; i++)
#pragma unroll
        for (int j = 0; j < 8; j++) acc[i][j] = 0.0f;

    for (int k0 = 0; k0 < CH; k0 += 16) {
        __syncthreads();
#pragma unroll
        for (int j = 0; j < 4; j++) {
            As[kc+j][r]    = ((const float*)&a0)[j];
            As[kc+j][r+64] = ((const float*)&a1)[j];
            Bs[kc+j][r]    = ((const float*)&b0)[j];
            Bs[kc+j][r+64] = ((const float*)&b1)[j];
        }
        __syncthreads();
        if (k0 + 16 < CH) {
            a0 = *(const float4*)(ApL + k0 + 16);
            a1 = *(const float4*)(ApH + k0 + 16);
            b0 = *(const float4*)(BpL + k0 + 16);
            b1 = *(const float4*)(BpH + k0 + 16);
        }
#pragma unroll
        for (int kk = 0; kk < 16; kk++) {
            float4 x0 = *(const float4*)&As[kk][ty*4];
            float4 x1 = *(const float4*)&As[kk][64 + ty*4];
            float4 y0 = *(const float4*)&Bs[kk][tx*4];
            float4 y1 = *(const float4*)&Bs[kk][64 + tx*4];
            float a[8]  = {x0.x,x0.y,x0.z,x0.w,x1.x,x1.y,x1.z,x1.w};
            float bb[8] = {y0.x,y0.y,y0.z,y0.w,y1.x,y1.y,y1.z,y1.w};
#pragma unroll
            for (int i = 0; i < 8; i++)
#pragma unroll
                for (int j = 0; j < 8; j++)
                    acc[i][j] = fmaf(a[i], bb[j], acc[i][j]);
        }
    }

#pragma unroll
    for (int i = 0; i < 8; i++) {
        const int row = m0 + ty*4 + (i & 3) + ((i >> 2) * 64);
#pragma unroll
        for (int jg = 0; jg < 2; jg++) {
            const int col = n0 + jg*64 + tx*4;
            float4 o = make_float4(acc[i][jg*4+0], acc[i][jg*4+1],
                                   acc[i][jg*4+2], acc[i][jg*4+3]);
            *(float4*)&C[(i64)row * (3*CH) + col] = o;
        }
    }
}

// ---------------- scores GEMM: one-shot BK=64 (K=DH), padded LDS -----------
__global__ __launch_bounds__(256)
void gemm_scores(const float* __restrict__ qkv, float* __restrict__ scores,
                 int b_base, i64 sC)
{
    __shared__ __align__(16) float As[64][132];
    __shared__ __align__(16) float Bs[64][132];
    const int tid = threadIdx.x;
    const int tx = tid & 15, ty = tid >> 4;
    const int m0 = blockIdx.y * 128, n0 = blockIdx.x * 128;
    const int b = b_base + blockIdx.z / NH, h = blockIdx.z % NH;

    const float* A = qkv + (i64)b * SEQ * (3*CH) + h * DH;   // q rows
    const float* B = A + CH;                                  // k rows
    float* C = scores + (i64)blockIdx.z * sC;

    // loader: 4 threads/row; thread's 4 float4s at k = (tid&3)*4 + c*16
    // (interleaved so LDS column-stores land 2-way with the 132 pad)
    const int lrow = tid >> 2;
    const int lk4 = (tid & 3) * 4;
    {
        float4 av[2][4], bv[2][4];
#pragma unroll
        for (int g = 0; g < 2; g++) {
            int ar = m0 + g*64 + lrow; if (ar > SEQ-1) ar = SEQ-1;
            int br = n0 + g*64 + lrow; if (br > SEQ-1) br = SEQ-1;
            const float* Ap = A + (i64)ar * (3*CH) + lk4;
            const float* Bp = B + (i64)br * (3*CH) + lk4;
#pragma unroll
            for (int c = 0; c < 4; c++) {
                av[g][c] = *(const float4*)(Ap + c*16);
                bv[g][c] = *(const float4*)(Bp + c*16);
            }
        }
#pragma unroll
        for (int g = 0; g < 2; g++)
#pragma unroll
            for (int c = 0; c < 4; c++)
#pragma unroll
                for (int j = 0; j < 4; j++) {
                    As[lk4 + c*16 + j][g*64 + lrow] = ((const float*)&av[g][c])[j];
                    Bs[lk4 + c*16 + j][g*64 + lrow] = ((const float*)&bv[g][c])[j];
                }
    }
    __syncthreads();

    float acc[8][8];
#pragma unroll
    for (int i = 0; i < 8; i++)
#pragma unroll
        for (int j = 0; j < 8; j++) acc[i][j] = 0.0f;

#pragma unroll 8
    for (int kk = 0; kk < 64; kk++) {
        float4 x0 = *(const float4*)&As[kk][ty*4];
        float4 x1 = *(const float4*)&As[kk][64 + ty*4];
        float4 y0 = *(const float4*)&Bs[kk][tx*4];
        float4 y1 = *(const float4*)&Bs[kk][64 + tx*4];
        float a[8]  = {x0.x,x0.y,x0.z,x0.w,x1.x,x1.y,x1.z,x1.w};
        float bb[8] = {y0.x,y0.y,y0.z,y0.w,y1.x,y1.y,y1.z,y1.w};
#pragma unroll
        for (int i = 0; i < 8; i++)
#pragma unroll
            for (int j = 0; j < 8; j++)
                acc[i][j] = fmaf(a[i], bb[j], acc[i][j]);
    }

#pragma unroll
    for (int i = 0; i < 8; i++) {
        const int row = m0 + ty*4 + (i & 3) + ((i >> 2) * 64);
        if (row >= SEQ) continue;
#pragma unroll
        for (int jg = 0; jg < 2; jg++) {
            const int col = n0 + jg*64 + tx*4;
            if (col >= SEQ) continue;
            float4 o = make_float4(0.125f*acc[i][jg*4+0], 0.125f*acc[i][jg*4+1],
                                   0.125f*acc[i][jg*4+2], 0.125f*acc[i][jg*4+3]);
            *(float4*)&C[(i64)row * SEQ + col] = o;
        }
    }
}

// ---------------- proj: bf16 MFMA (unchanged, verified R3) -----------------
__global__ __launch_bounds__(256)
void gemm_proj(const unsigned short* __restrict__ Abf,
               const unsigned short* __restrict__ Bbf,
               const float* __restrict__ bias, float* __restrict__ C)
{
    __shared__ __align__(16) unsigned short As[128 * 40];
    __shared__ __align__(16) unsigned short Bs[128 * 40];
    const int tid = threadIdx.x;
    const int lane = tid & 63, w = tid >> 6;
    const int wm = (w >> 1) * 64, wn = (w & 1) * 64;
    const int m0 = blockIdx.y * 128, n0 = blockIdx.x * 128;

    f32x4 acc[4][4];
#pragma unroll
    for (int i = 0; i < 4; i++)
#pragma unroll
        for (int j = 0; j < 4; j++) acc[i][j] = (f32x4){0.f,0.f,0.f,0.f};

    const int q = lane >> 4;
    const int rA = lane & 15;

    for (int k0 = 0; k0 < CH; k0 += 32) {
        __syncthreads();
#pragma unroll
        for (int rep = 0; rep < 2; rep++) {
            const int id = rep * 256 + tid;
            const int row = id >> 2, c = id & 3;
            *(uint4*)&As[row*40 + c*8] = *(const uint4*)&Abf[(i64)(m0+row)*CH + k0 + c*8];
            *(uint4*)&Bs[row*40 + c*8] = *(const uint4*)&Bbf[(i64)(n0+row)*CH + k0 + c*8];
        }
        __syncthreads();
#pragma unroll
        for (int mt = 0; mt < 4; mt++) {
            bf16x8 a = *(const bf16x8*)&As[(wm + mt*16 + rA)*40 + q*8];
#pragma unroll
            for (int nt = 0; nt < 4; nt++) {
                bf16x8 b = *(const bf16x8*)&Bs[(wn + nt*16 + rA)*40 + q*8];
                acc[mt][nt] = __builtin_amdgcn_mfma_f32_16x16x32_bf16(a, b, acc[mt][nt], 0, 0, 0);
            }
        }
    }

#pragma unroll
    for (int mt = 0; mt < 4; mt++)
#pragma unroll
        for (int nt = 0; nt < 4; nt++) {
            const int col = n0 + wn + nt*16 + (lane & 15);
            const float bcol = bias[col];
#pragma unroll
            for (int rg = 0; rg < 4; rg++) {
                const int row = m0 + wm + mt*16 + (lane >> 4)*4 + rg;
                C[(i64)row * CH + col] = acc[mt][nt][rg] + bcol;
            }
        }
}

__global__ __launch_bounds__(256)
void cast_w(const float* __restrict__ src, unsigned short* __restrict__ dst, int n4)
{
    int i = blockIdx.x * 256 + threadIdx.x;
    if (i >= n4) return;
    float4 v = *(const float4*)&src[i*4];
    unsigned short o[4];
    o[0] = __bfloat16_as_ushort(__float2bfloat16(v.x));
    o[1] = __bfloat16_as_ushort(__float2bfloat16(v.y));
    o[2] = __bfloat16_as_ushort(__float2bfloat16(v.z));
    o[3] = __bfloat16_as_ushort(__float2bfloat16(v.w));
    *(uint2*)&dst[i*4] = *(uint2*)o;
}

// ---------------- top-k select: atomic-storm-free radix --------------------
__device__ __forceinline__ float wave_fsum(float v) {
#pragma unroll
    for (int m = 32; m; m >>= 1) v += __shfl_xor(v, m, 64);
    return v;
}
__device__ __forceinline__ int wave_isum(int v) {
#pragma unroll
    for (int m = 32; m; m >>= 1) v += __shfl_xor(v, m, 64);
    return v;
}
__device__ __forceinline__ unsigned fkey(float t) {
    unsigned bits = __float_as_uint(t);
    return (bits & 0x80000000u) ? ~bits : (bits | 0x80000000u);
}

__global__ __launch_bounds__(256)
void select_topk(const float* __restrict__ scores, i64 sstride,
                 const float* __restrict__ ucb_cnt,
                 const float* __restrict__ qkv,
                 unsigned short* __restrict__ ctxbf,
                 float* __restrict__ sdelta,
                 const int* __restrict__ counter_p,
                 int b0, int b1)
{
    __shared__ __align__(16) unsigned u_vals[SEQ];   // only for rare tie path
    __shared__ unsigned char selflag[SEQ];
    __shared__ unsigned hist[256];
    __shared__ unsigned wtot[4];
    __shared__ float    fred[4];
    __shared__ int      ired[4];
    __shared__ float    cred[256];
    __shared__ float    wsel[K_TOP + 4];
    __shared__ int      isel[K_TOP + 4];
    __shared__ unsigned sh_prefix;
    __shared__ int      sh_r;

    const int tid = threadIdx.x;
    const int lane = tid & 63, wid = tid >> 6;
    const int n = blockIdx.x, h = blockIdx.y;
    const float L = logf((float)(*counter_p));
    const i64 rowoff = ((i64)h * SEQ + n) * SEQ;
    const bool owner = tid < NE4;
    const unsigned long long lt = (1ull << lane) - 1ull;

    float4 bon = make_float4(0.f,0.f,0.f,0.f);
    if (owner) {
        float4 c4 = *(const float4*)&ucb_cnt[rowoff + tid*4];
        bon.x = sqrtf(L / (c4.x + 1e-6f));
        bon.y = sqrtf(L / (c4.y + 1e-6f));
        bon.z = sqrtf(L / (c4.z + 1e-6f));
        bon.w = sqrtf(L / (c4.w + 1e-6f));
    }
    int cnt_acc[4] = {0,0,0,0};
    hist[tid] = 0u;

    for (int b = b0; b < b1; b++) {
        float4 s4 = make_float4(0.f,0.f,0.f,0.f);
        unsigned uv[4] = {0u,0u,0u,0u};
        if (owner) {
            s4 = *(const float4*)&(scores + (i64)(b - b0) * sstride + rowoff)[tid*4];
            uv[0] = fkey(s4.x + bon.x);
            uv[1] = fkey(s4.y + bon.y);
            uv[2] = fkey(s4.z + bon.z);
            uv[3] = fkey(s4.w + bon.w);
            *(uint4*)&u_vals[tid*4] = make_uint4(uv[0],uv[1],uv[2],uv[3]);
            *(uchar4*)&selflag[tid*4] = make_uchar4(0,0,0,0);
        }
        __syncthreads();   // hist zero + u_vals/selflag visible

        // ---- 4-pass 8-bit MSB radix select, leader-aggregated histogram ----
        unsigned prefix = 0u; int r = K_TOP;
#pragma unroll
        for (int pass = 3; pass >= 0; pass--) {
            const int shift = pass * 8;
            const unsigned mask_hi = (pass == 3) ? 0u : (0xFFFFFFFFu << (shift + 8));
#pragma unroll
            for (int j = 0; j < 4; j++) {
                const bool act = owner && ((uv[j] & mask_hi) == prefix);
                const unsigned d = (uv[j] >> shift) & 255u;
                unsigned long long m = __ballot(act);
                while (m) {   // one atomic per UNIQUE digit per wave
                    const int src = __ffsll((unsigned long long)m) - 1;
                    const unsigned dd = __shfl(d, src, 64);
                    const unsigned long long eq = __ballot(act && d == dd);
                    if (lane == src) atomicAdd(&hist[dd], (unsigned)__popcll(eq));
                    m &= ~eq;
                }
            }
            __syncthreads();
            const unsigned hme = hist[tid];
            unsigned ssum = hme;          // wave inclusive suffix scan
#pragma unroll
            for (int off = 1; off < 64; off <<= 1) {
                unsigned t = __shfl_down(ssum, off, 64);
                if (lane + off < 64) ssum += t;
            }
            if (lane == 0) wtot[wid] = ssum;
            __syncthreads();
            unsigned above = 0;
            for (int ww = wid + 1; ww < 4; ww++) above += wtot[ww];
            const unsigned cge = ssum + above;
            const unsigned cgt = cge - hme;
            if ((int)cge >= r && (int)cgt < r) {
                sh_prefix = prefix | ((unsigned)tid << shift);
                sh_r = r - (int)cgt;
            }
            hist[tid] = 0u;
            __syncthreads();
            prefix = sh_prefix; r = sh_r;
        }
        const unsigned T = prefix;
        const int rfin = r;

        // ---- flags: u > T in; count equals for tie resolution ----
        int myeq = 0;
        if (owner) {
#pragma unroll
            for (int j = 0; j < 4; j++) {
                if (uv[j] > T) selflag[tid*4 + j] = 1;
                myeq += (uv[j] == T);
            }
        }
        int weq = wave_isum(myeq);
        if (lane == 0) ired[wid] = weq;
        __syncthreads();
        const int ceq = ired[0] + ired[1] + ired[2] + ired[3];
        if (ceq == rfin) {
            if (owner) {
#pragma unroll
                for (int j = 0; j < 4; j++)
                    if (uv[j] == T) selflag[tid*4 + j] = 1;
            }
        } else if (tid == 0) {   // rare duplicate-key tie: stable by lowest idx
            int nd = rfin;
            for (int m = 0; m < SEQ && nd > 0; m++)
                if (u_vals[m] == T) { selflag[m] = 1; nd--; }
        }
        __syncthreads();

        // ---- compaction via ballot prefix-sum (no atomics, exact order) ----
        int selr[4];
        if (owner) {
            uchar4 fl = *(const uchar4*)&selflag[tid*4];
            selr[0] = fl.x; selr[1] = fl.y; selr[2] = fl.z; selr[3] = fl.w;
        } else selr[0] = selr[1] = selr[2] = selr[3] = 0;
        unsigned long long bj[4];
        int wsum = 0, before = 0;
#pragma unroll
        for (int j = 0; j < 4; j++) {
            bj[j] = __ballot(selr[j] != 0);
            wsum   += (int)__popcll(bj[j]);
            before += (int)__popcll(bj[j] & lt);
        }
        if (lane == 0) ired[wid] = wsum;
        __syncthreads();
        int pos = before;
        for (int ww = 0; ww < wid; ww++) pos += ired[ww];
        float pw = 0.f;
#pragma unroll
        for (int j = 0; j < 4; j++) {
            if (selr[j]) {
                isel[pos] = tid*4 + j;
                wsel[pos] = ((const float*)&s4)[j];
                pos++;
                pw += ((const float*)&s4)[j];
                cnt_acc[j]++;
            }
        }
        float w0 = wave_fsum(pw);
        if (lane == 0) fred[wid] = w0;
        __syncthreads();   // isel/wsel/fred visible
        const float inv = 1.0f / (fred[0] + fred[1] + fred[2] + fred[3] + 1e-8f);

        // ---- context gather: exactly K_TOP selected rows ----
        const int d = tid & 63, g = tid >> 6;
        float acc = 0.f;
        const float* vbase = qkv + (i64)b * SEQ * (3*CH) + 2*CH + h * DH + d;
        for (int j = g; j < K_TOP; j += 4)
            acc += wsel[j] * vbase[(i64)isel[j] * (3*CH)];
        cred[tid] = acc;
        __syncthreads();
        if (tid < 64) {
            float tot = cred[tid] + cred[tid+64] + cred[tid+128] + cred[tid+192];
            ctxbf[((i64)b * SEQ + n) * CH + h * DH + tid] =
                __bfloat16_as_ushort(__float2bfloat16(inv * tot));
        }
        __syncthreads();   // LDS reused next b
    }

    if (owner) {
        float4 o;
        o.x = (float)cnt_acc[0]; o.y = (float)cnt_acc[1];
        o.z = (float)cnt_acc[2]; o.w = (float)cnt_acc[3];
        float* dst = &sdelta[rowoff + tid*4];
        if (b0 != 0) {
            float4 p = *(const float4*)dst;
            o.x += p.x; o.y += p.y; o.z += p.z; o.w += p.w;
        }
        *(float4*)dst = o;
    }
}

extern "C" void kernel_launch(void* const* d_in, const int* in_sizes, int n_in,
                              void* d_out, int out_size, void* d_ws, size_t ws_size,
                              hipStream_t stream) {
    const float* x      = (const float*)d_in[0];
    const float* ucb    = (const float*)d_in[1];
    const float* qkv_w  = (const float*)d_in[2];
    const float* proj_w = (const float*)d_in[3];
    const float* proj_b = (const float*)d_in[4];
    const int*   counter = (const int*)d_in[5];

    float* out0   = (float*)d_out;
    float* sdelta = out0 + (i64)NB * SEQ * CH;

    const size_t qkv_f  = (size_t)NB * SEQ * (3*CH);
    const size_t ctx_h  = (size_t)NB * SEQ * CH;
    const size_t w_h    = (size_t)CH * CH;

    float* qkv_buf = (float*)d_ws;
    unsigned short* ctx_bf = (unsigned short*)(qkv_buf + qkv_f);
    unsigned short* w_bf   = ctx_bf + ctx_h;
    size_t off = ((qkv_f * 4 + (ctx_h + w_h) * 2) + 15) & ~(size_t)15;
    float* scores = (float*)((char*)d_ws + off);

    // adaptive: how many batches of score planes fit in remaining scratch?
    const size_t per_b = (size_t)NH * SEQ * SEQ * 4;
    int nbc = (ws_size > off) ? (int)((ws_size - off) / per_b) : 1;
    if (nbc < 1) nbc = 1;
    if (nbc > NB) nbc = NB;

    dim3 blk(256);

    cast_w<<<dim3((CH*CH/4 + 255)/256), blk, 0, stream>>>(proj_w, w_bf, CH*CH/4);
    gemm_qkv<<<dim3(18, 49), blk, 0, stream>>>(x, qkv_w, qkv_buf);

    for (int b0 = 0; b0 < NB; b0 += nbc) {
        const int bn = (b0 + nbc <= NB) ? nbc : (NB - b0);
        gemm_scores<<<dim3(7, 7, bn*NH), blk, 0, stream>>>(
            qkv_buf, scores, b0, (i64)SEQ*SEQ);
        select_topk<<<dim3(SEQ, NH), blk, 0, stream>>>(
            scores, (i64)NH*SEQ*SEQ, ucb, qkv_buf, ctx_bf, sdelta, counter,
            b0, b0 + bn);
    }

    gemm_proj<<<dim3(6, 49), blk, 0, stream>>>(ctx_bf, w_bf, proj_b, out0);
}

// Round 5
// 1238.082 us; speedup vs baseline: 1.3384x; 1.3384x over previous
//
#include <hip/hip_runtime.h>
#include <hip/hip_bf16.h>
#include <math.h>

#define NB 8
#define NH 12
#define SEQ 784
#define CH 768
#define DH 64
#define K_TOP 100
#define NE4 196   // SEQ/4

typedef long long i64;
typedef __attribute__((ext_vector_type(8))) short bf16x8;
typedef __attribute__((ext_vector_type(4))) float f32x4;

// ---------------- QKV GEMM: C = A @ B^T, fp32 vector, BK=16, padded LDS ----
__global__ __launch_bounds__(256)
void gemm_qkv(const float* __restrict__ A, const float* __restrict__ B,
              float* __restrict__ C)
{
    __shared__ __align__(16) float As[16][132];
    __shared__ __align__(16) float Bs[16][132];
    const int tid = threadIdx.x;
    const int tx = tid & 15, ty = tid >> 4;
    const int m0 = blockIdx.y * 128, n0 = blockIdx.x * 128;

    const int r  = tid >> 2;
    const int kc = (tid & 3) << 2;
    const float* ApL = A + (i64)(m0 + r)      * CH + kc;
    const float* ApH = A + (i64)(m0 + r + 64) * CH + kc;
    const float* BpL = B + (i64)(n0 + r)      * CH + kc;
    const float* BpH = B + (i64)(n0 + r + 64) * CH + kc;

    float4 a0 = *(const float4*)ApL, a1 = *(const float4*)ApH;
    float4 b0 = *(const float4*)BpL, b1 = *(const float4*)BpH;

    float acc[8][8];
#pragma unroll
    for (int i = 0; i < 8; i++)
#pragma unroll
        for (int j = 0; j < 8; j++) acc[i][j] = 0.0f;

    for (int k0 = 0; k0 < CH; k0 += 16) {
        __syncthreads();
#pragma unroll
        for (int j = 0; j < 4; j++) {
            As[kc+j][r]    = ((const float*)&a0)[j];
            As[kc+j][r+64] = ((const float*)&a1)[j];
            Bs[kc+j][r]    = ((const float*)&b0)[j];
            Bs[kc+j][r+64] = ((const float*)&b1)[j];
        }
        __syncthreads();
        if (k0 + 16 < CH) {
            a0 = *(const float4*)(ApL + k0 + 16);
            a1 = *(const float4*)(ApH + k0 + 16);
            b0 = *(const float4*)(BpL + k0 + 16);
            b1 = *(const float4*)(BpH + k0 + 16);
        }
#pragma unroll
        for (int kk = 0; kk < 16; kk++) {
            float4 x0 = *(const float4*)&As[kk][ty*4];
            float4 x1 = *(const float4*)&As[kk][64 + ty*4];
            float4 y0 = *(const float4*)&Bs[kk][tx*4];
            float4 y1 = *(const float4*)&Bs[kk][64 + tx*4];
            float a[8]  = {x0.x,x0.y,x0.z,x0.w,x1.x,x1.y,x1.z,x1.w};
            float bb[8] = {y0.x,y0.y,y0.z,y0.w,y1.x,y1.y,y1.z,y1.w};
#pragma unroll
            for (int i = 0; i < 8; i++)
#pragma unroll
                for (int j = 0; j < 8; j++)
                    acc[i][j] = fmaf(a[i], bb[j], acc[i][j]);
        }
    }

#pragma unroll
    for (int i = 0; i < 8; i++) {
        const int row = m0 + ty*4 + (i & 3) + ((i >> 2) * 64);
#pragma unroll
        for (int jg = 0; jg < 2; jg++) {
            const int col = n0 + jg*64 + tx*4;
            float4 o = make_float4(acc[i][jg*4+0], acc[i][jg*4+1],
                                   acc[i][jg*4+2], acc[i][jg*4+3]);
            *(float4*)&C[(i64)row * (3*CH) + col] = o;
        }
    }
}

// ---------------- scores GEMM: K=64 in two BK=32 phases, 4 blocks/CU -------
__global__ __launch_bounds__(256)
void gemm_scores(const float* __restrict__ qkv, float* __restrict__ scores,
                 int b_base, i64 sC)
{
    __shared__ __align__(16) float As[32][132];   // 16.9 KB
    __shared__ __align__(16) float Bs[32][132];   // total 33.8 KB -> 4 blk/CU
    const int tid = threadIdx.x;
    const int tx = tid & 15, ty = tid >> 4;
    const int m0 = blockIdx.y * 128, n0 = blockIdx.x * 128;
    const int b = b_base + blockIdx.z / NH, h = blockIdx.z % NH;

    const float* A = qkv + (i64)b * SEQ * (3*CH) + h * DH;   // q rows
    const float* B = A + CH;                                  // k rows
    float* C = scores + (i64)blockIdx.z * sC;

    const int lrow = tid >> 2;
    const int lk4 = (tid & 3) * 4;   // 0,4,8,12
    const float* Aro[2];
    const float* Bro[2];
#pragma unroll
    for (int g = 0; g < 2; g++) {
        int ar = m0 + g*64 + lrow; if (ar > SEQ-1) ar = SEQ-1;
        int br = n0 + g*64 + lrow; if (br > SEQ-1) br = SEQ-1;
        Aro[g] = A + (i64)ar * (3*CH);
        Bro[g] = B + (i64)br * (3*CH);
    }

    float4 av[2][2], bv[2][2];
    // phase-0 chunk: k in [0,32): offsets lk4 + 16*c
#pragma unroll
    for (int g = 0; g < 2; g++)
#pragma unroll
        for (int c = 0; c < 2; c++) {
            av[g][c] = *(const float4*)(Aro[g] + lk4 + c*16);
            bv[g][c] = *(const float4*)(Bro[g] + lk4 + c*16);
        }

    float acc[8][8];
#pragma unroll
    for (int i = 0; i < 8; i++)
#pragma unroll
        for (int j = 0; j < 8; j++) acc[i][j] = 0.0f;

#pragma unroll
    for (int ph = 0; ph < 2; ph++) {
        if (ph) __syncthreads();   // compute of phase 0 done before overwrite
#pragma unroll
        for (int g = 0; g < 2; g++)
#pragma unroll
            for (int c = 0; c < 2; c++)
#pragma unroll
                for (int j = 0; j < 4; j++) {
                    As[lk4 + c*16 + j][g*64 + lrow] = ((const float*)&av[g][c])[j];
                    Bs[lk4 + c*16 + j][g*64 + lrow] = ((const float*)&bv[g][c])[j];
                }
        __syncthreads();
        if (ph == 0) {   // prefetch phase-1 chunk (k in [32,64)) before compute
#pragma unroll
            for (int g = 0; g < 2; g++)
#pragma unroll
                for (int c = 0; c < 2; c++) {
                    av[g][c] = *(const float4*)(Aro[g] + 32 + lk4 + c*16);
                    bv[g][c] = *(const float4*)(Bro[g] + 32 + lk4 + c*16);
                }
        }
#pragma unroll 8
        for (int kk = 0; kk < 32; kk++) {
            float4 x0 = *(const float4*)&As[kk][ty*4];
            float4 x1 = *(const float4*)&As[kk][64 + ty*4];
            float4 y0 = *(const float4*)&Bs[kk][tx*4];
            float4 y1 = *(const float4*)&Bs[kk][64 + tx*4];
            float a[8]  = {x0.x,x0.y,x0.z,x0.w,x1.x,x1.y,x1.z,x1.w};
            float bb[8] = {y0.x,y0.y,y0.z,y0.w,y1.x,y1.y,y1.z,y1.w};
#pragma unroll
            for (int i = 0; i < 8; i++)
#pragma unroll
                for (int j = 0; j < 8; j++)
                    acc[i][j] = fmaf(a[i], bb[j], acc[i][j]);
        }
    }

#pragma unroll
    for (int i = 0; i < 8; i++) {
        const int row = m0 + ty*4 + (i & 3) + ((i >> 2) * 64);
        if (row >= SEQ) continue;
#pragma unroll
        for (int jg = 0; jg < 2; jg++) {
            const int col = n0 + jg*64 + tx*4;
            if (col >= SEQ) continue;
            float4 o = make_float4(0.125f*acc[i][jg*4+0], 0.125f*acc[i][jg*4+1],
                                   0.125f*acc[i][jg*4+2], 0.125f*acc[i][jg*4+3]);
            *(float4*)&C[(i64)row * SEQ + col] = o;
        }
    }
}

// ---------------- proj: bf16 MFMA (verified R3) ----------------------------
__global__ __launch_bounds__(256)
void gemm_proj(const unsigned short* __restrict__ Abf,
               const unsigned short* __restrict__ Bbf,
               const float* __restrict__ bias, float* __restrict__ C)
{
    __shared__ __align__(16) unsigned short As[128 * 40];
    __shared__ __align__(16) unsigned short Bs[128 * 40];
    const int tid = threadIdx.x;
    const int lane = tid & 63, w = tid >> 6;
    const int wm = (w >> 1) * 64, wn = (w & 1) * 64;
    const int m0 = blockIdx.y * 128, n0 = blockIdx.x * 128;

    f32x4 acc[4][4];
#pragma unroll
    for (int i = 0; i < 4; i++)
#pragma unroll
        for (int j = 0; j < 4; j++) acc[i][j] = (f32x4){0.f,0.f,0.f,0.f};

    const int q = lane >> 4;
    const int rA = lane & 15;

    for (int k0 = 0; k0 < CH; k0 += 32) {
        __syncthreads();
#pragma unroll
        for (int rep = 0; rep < 2; rep++) {
            const int id = rep * 256 + tid;
            const int row = id >> 2, c = id & 3;
            *(uint4*)&As[row*40 + c*8] = *(const uint4*)&Abf[(i64)(m0+row)*CH + k0 + c*8];
            *(uint4*)&Bs[row*40 + c*8] = *(const uint4*)&Bbf[(i64)(n0+row)*CH + k0 + c*8];
        }
        __syncthreads();
#pragma unroll
        for (int mt = 0; mt < 4; mt++) {
            bf16x8 a = *(const bf16x8*)&As[(wm + mt*16 + rA)*40 + q*8];
#pragma unroll
            for (int nt = 0; nt < 4; nt++) {
                bf16x8 b = *(const bf16x8*)&Bs[(wn + nt*16 + rA)*40 + q*8];
                acc[mt][nt] = __builtin_amdgcn_mfma_f32_16x16x32_bf16(a, b, acc[mt][nt], 0, 0, 0);
            }
        }
    }

#pragma unroll
    for (int mt = 0; mt < 4; mt++)
#pragma unroll
        for (int nt = 0; nt < 4; nt++) {
            const int col = n0 + wn + nt*16 + (lane & 15);
            const float bcol = bias[col];
#pragma unroll
            for (int rg = 0; rg < 4; rg++) {
                const int row = m0 + wm + mt*16 + (lane >> 4)*4 + rg;
                C[(i64)row * CH + col] = acc[mt][nt][rg] + bcol;
            }
        }
}

__global__ __launch_bounds__(256)
void cast_w(const float* __restrict__ src, unsigned short* __restrict__ dst, int n4)
{
    int i = blockIdx.x * 256 + threadIdx.x;
    if (i >= n4) return;
    float4 v = *(const float4*)&src[i*4];
    unsigned short o[4];
    o[0] = __bfloat16_as_ushort(__float2bfloat16(v.x));
    o[1] = __bfloat16_as_ushort(__float2bfloat16(v.y));
    o[2] = __bfloat16_as_ushort(__float2bfloat16(v.z));
    o[3] = __bfloat16_as_ushort(__float2bfloat16(v.w));
    *(uint2*)&dst[i*4] = *(uint2*)o;
}

// ---------------- top-k select: HYBRID radix + early exit ------------------
// Pass 3 (exponent byte, clustered): ballot-dedup -> few iterations.
// Passes 2..0 (mantissa bytes, spread): plain LDS atomicAdd -> few collisions.
// Early exit when chosen bin count == remaining rank (typical by pass 2).
__device__ __forceinline__ float wave_fsum(float v) {
#pragma unroll
    for (int m = 32; m; m >>= 1) v += __shfl_xor(v, m, 64);
    return v;
}
__device__ __forceinline__ int wave_isum(int v) {
#pragma unroll
    for (int m = 32; m; m >>= 1) v += __shfl_xor(v, m, 64);
    return v;
}
__device__ __forceinline__ unsigned fkey(float t) {
    unsigned bits = __float_as_uint(t);
    return (bits & 0x80000000u) ? ~bits : (bits | 0x80000000u);
}

__global__ __launch_bounds__(256)
void select_topk(const float* __restrict__ scores, i64 sstride,
                 const float* __restrict__ ucb_cnt,
                 const float* __restrict__ qkv,
                 unsigned short* __restrict__ ctxbf,
                 float* __restrict__ sdelta,
                 const int* __restrict__ counter_p,
                 int b0, int b1)
{
    __shared__ __align__(16) unsigned u_vals[SEQ];   // rare tie path only
    __shared__ unsigned char selflag[SEQ];
    __shared__ unsigned hist[256];
    __shared__ unsigned wtot[4];
    __shared__ float    fred[4];
    __shared__ int      ired[4];
    __shared__ float    cred[256];
    __shared__ float    wsel[K_TOP + 4];
    __shared__ int      isel[K_TOP + 4];
    __shared__ unsigned sh_prefix;
    __shared__ int      sh_r, sh_done;

    const int tid = threadIdx.x;
    const int lane = tid & 63, wid = tid >> 6;
    const int n = blockIdx.x, h = blockIdx.y;
    const float L = logf((float)(*counter_p));
    const i64 rowoff = ((i64)h * SEQ + n) * SEQ;
    const bool owner = tid < NE4;
    const unsigned long long lt = (1ull << lane) - 1ull;

    float4 bon = make_float4(0.f,0.f,0.f,0.f);
    if (owner) {
        float4 c4 = *(const float4*)&ucb_cnt[rowoff + tid*4];
        bon.x = sqrtf(L / (c4.x + 1e-6f));
        bon.y = sqrtf(L / (c4.y + 1e-6f));
        bon.z = sqrtf(L / (c4.z + 1e-6f));
        bon.w = sqrtf(L / (c4.w + 1e-6f));
    }
    int cnt_acc[4] = {0,0,0,0};
    hist[tid] = 0u;

    for (int b = b0; b < b1; b++) {
        float4 s4 = make_float4(0.f,0.f,0.f,0.f);
        unsigned uv[4] = {0u,0u,0u,0u};
        if (tid == 0) { sh_prefix = 0u; sh_r = K_TOP; sh_done = 0; }
        if (owner) {
            s4 = *(const float4*)&(scores + (i64)(b - b0) * sstride + rowoff)[tid*4];
            uv[0] = fkey(s4.x + bon.x);
            uv[1] = fkey(s4.y + bon.y);
            uv[2] = fkey(s4.z + bon.z);
            uv[3] = fkey(s4.w + bon.w);
            *(uint4*)&u_vals[tid*4] = make_uint4(uv[0],uv[1],uv[2],uv[3]);
            *(uchar4*)&selflag[tid*4] = make_uchar4(0,0,0,0);
        }
        __syncthreads();

        unsigned prefix = 0u; int r = K_TOP;
        bool geq_mode = false;
        int final_shift = 0;
        for (int pass = 3; pass >= 0; pass--) {
            const int shift = pass * 8;
            if (pass == 3) {
                // clustered digits -> ballot-dedup (few unique values)
#pragma unroll
                for (int j = 0; j < 4; j++) {
                    const bool act = owner;
                    const unsigned d = uv[j] >> 24;
                    unsigned long long m = __ballot(act);
                    while (m) {
                        const int src = __ffsll((unsigned long long)m) - 1;
                        const unsigned dd = __shfl(d, src, 64);
                        const unsigned long long eq = __ballot(act && d == dd);
                        if (lane == src) atomicAdd(&hist[dd], (unsigned)__popcll(eq));
                        m &= ~eq;
                    }
                }
            } else {
                // spread digits -> plain atomics (near-zero collisions)
                const unsigned mask_hi = 0xFFFFFFFFu << (shift + 8);
                if (owner) {
#pragma unroll
                    for (int j = 0; j < 4; j++) {
                        unsigned u = uv[j];
                        if ((u & mask_hi) == prefix)
                            atomicAdd(&hist[(u >> shift) & 255u], 1u);
                    }
                }
            }
            __syncthreads();
            const unsigned hme = hist[tid];
            unsigned ssum = hme;
#pragma unroll
            for (int off = 1; off < 64; off <<= 1) {
                unsigned t = __shfl_down(ssum, off, 64);
                if (lane + off < 64) ssum += t;
            }
            if (lane == 0) wtot[wid] = ssum;
            __syncthreads();
            unsigned above = 0;
            for (int ww = wid + 1; ww < 4; ww++) above += wtot[ww];
            const unsigned cge = ssum + above;
            const unsigned cgt = cge - hme;
            if ((int)cge >= r && (int)cgt < r) {
                sh_prefix = prefix | ((unsigned)tid << shift);
                sh_r = r - (int)cgt;
                if (hme == (unsigned)(r - (int)cgt)) sh_done = 1;  // whole bin in
            }
            hist[tid] = 0u;
            __syncthreads();
            prefix = sh_prefix; r = sh_r;
            if (sh_done) { geq_mode = true; final_shift = shift; break; }
        }
        const unsigned T = prefix;
        const int rfin = r;

        // ---- selection flags ----
        if (geq_mode) {
            // exactly K_TOP keys have u >= T (T low bits below final_shift are 0)
            (void)final_shift;
            if (owner) {
#pragma unroll
                for (int j = 0; j < 4; j++)
                    if (uv[j] >= T) selflag[tid*4 + j] = 1;
            }
            __syncthreads();
        } else {
            int myeq = 0;
            if (owner) {
#pragma unroll
                for (int j = 0; j < 4; j++) {
                    if (uv[j] > T) selflag[tid*4 + j] = 1;
                    myeq += (uv[j] == T);
                }
            }
            int weq = wave_isum(myeq);
            if (lane == 0) ired[wid] = weq;
            __syncthreads();
            const int ceq = ired[0] + ired[1] + ired[2] + ired[3];
            if (ceq == rfin) {
                if (owner) {
#pragma unroll
                    for (int j = 0; j < 4; j++)
                        if (uv[j] == T) selflag[tid*4 + j] = 1;
                }
            } else if (tid == 0) {   // rare duplicate-key tie: lowest index first
                int nd = rfin;
                for (int m = 0; m < SEQ && nd > 0; m++)
                    if (u_vals[m] == T) { selflag[m] = 1; nd--; }
            }
            __syncthreads();
        }

        // ---- compaction via ballot prefix-sum (no atomics) ----
        int selr[4];
        if (owner) {
            uchar4 fl = *(const uchar4*)&selflag[tid*4];
            selr[0] = fl.x; selr[1] = fl.y; selr[2] = fl.z; selr[3] = fl.w;
        } else selr[0] = selr[1] = selr[2] = selr[3] = 0;
        unsigned long long bj[4];
        int wsum = 0, before = 0;
#pragma unroll
        for (int j = 0; j < 4; j++) {
            bj[j] = __ballot(selr[j] != 0);
            wsum   += (int)__popcll(bj[j]);
            before += (int)__popcll(bj[j] & lt);
        }
        if (lane == 0) ired[wid] = wsum;
        __syncthreads();
        int pos = before;
        for (int ww = 0; ww < wid; ww++) pos += ired[ww];
        float pw = 0.f;
#pragma unroll
        for (int j = 0; j < 4; j++) {
            if (selr[j]) {
                isel[pos] = tid*4 + j;
                wsel[pos] = ((const float*)&s4)[j];
                pos++;
                pw += ((const float*)&s4)[j];
                cnt_acc[j]++;
            }
        }
        float w0 = wave_fsum(pw);
        if (lane == 0) fred[wid] = w0;
        __syncthreads();
        const float inv = 1.0f / (fred[0] + fred[1] + fred[2] + fred[3] + 1e-8f);

        // ---- context gather: exactly K_TOP rows ----
        const int d = tid & 63, g = tid >> 6;
        float acc = 0.f;
        const float* vbase = qkv + (i64)b * SEQ * (3*CH) + 2*CH + h * DH + d;
        for (int j = g; j < K_TOP; j += 4)
            acc += wsel[j] * vbase[(i64)isel[j] * (3*CH)];
        cred[tid] = acc;
        __syncthreads();
        if (tid < 64) {
            float tot = cred[tid] + cred[tid+64] + cred[tid+128] + cred[tid+192];
            ctxbf[((i64)b * SEQ + n) * CH + h * DH + tid] =
                __bfloat16_as_ushort(__float2bfloat16(inv * tot));
        }
        __syncthreads();
    }

    if (owner) {
        float4 o;
        o.x = (float)cnt_acc[0]; o.y = (float)cnt_acc[1];
        o.z = (float)cnt_acc[2]; o.w = (float)cnt_acc[3];
        float* dst = &sdelta[rowoff + tid*4];
        if (b0 != 0) {
            float4 p = *(const float4*)dst;
            o.x += p.x; o.y += p.y; o.z += p.z; o.w += p.w;
        }
        *(float4*)dst = o;
    }
}

extern "C" void kernel_launch(void* const* d_in, const int* in_sizes, int n_in,
                              void* d_out, int out_size, void* d_ws, size_t ws_size,
                              hipStream_t stream) {
    const float* x      = (const float*)d_in[0];
    const float* ucb    = (const float*)d_in[1];
    const float* qkv_w  = (const float*)d_in[2];
    const float* proj_w = (const float*)d_in[3];
    const float* proj_b = (const float*)d_in[4];
    const int*   counter = (const int*)d_in[5];

    float* out0   = (float*)d_out;
    float* sdelta = out0 + (i64)NB * SEQ * CH;

    const size_t qkv_f  = (size_t)NB * SEQ * (3*CH);
    const size_t ctx_h  = (size_t)NB * SEQ * CH;
    const size_t w_h    = (size_t)CH * CH;

    float* qkv_buf = (float*)d_ws;
    unsigned short* ctx_bf = (unsigned short*)(qkv_buf + qkv_f);
    unsigned short* w_bf   = ctx_bf + ctx_h;
    size_t off = ((qkv_f * 4 + (ctx_h + w_h) * 2) + 15) & ~(size_t)15;
    float* scores = (float*)((char*)d_ws + off);

    const size_t per_b = (size_t)NH * SEQ * SEQ * 4;
    int nbc = (ws_size > off) ? (int)((ws_size - off) / per_b) : 1;
    if (nbc < 1) nbc = 1;
    if (nbc > NB) nbc = NB;

    dim3 blk(256);

    cast_w<<<dim3((CH*CH/4 + 255)/256), blk, 0, stream>>>(proj_w, w_bf, CH*CH/4);
    gemm_qkv<<<dim3(18, 49), blk, 0, stream>>>(x, qkv_w, qkv_buf);

    for (int b0 = 0; b0 < NB; b0 += nbc) {
        const int bn = (b0 + nbc <= NB) ? nbc : (NB - b0);
        gemm_scores<<<dim3(7, 7, bn*NH), blk, 0, stream>>>(
            qkv_buf, scores, b0, (i64)SEQ*SEQ);
        select_topk<<<dim3(SEQ, NH), blk, 0, stream>>>(
            scores, (i64)NH*SEQ*SEQ, ucb, qkv_buf, ctx_bf, sdelta, counter,
            b0, b0 + bn);
    }

    gemm_proj<<<dim3(6, 49), blk, 0, stream>>>(ctx_bf, w_bf, proj_b, out0);
}

// Round 6
// 952.009 us; speedup vs baseline: 1.7406x; 1.3005x over previous
//
#include <hip/hip_runtime.h>
#include <hip/hip_bf16.h>
#include <math.h>

#define NB 8
#define NH 12
#define SEQ 784
#define CH 768
#define DH 64
#define K_TOP 100
#define NSLOT 13   // ceil(784/64)

typedef long long i64;
typedef __attribute__((ext_vector_type(8))) short bf16x8;
typedef __attribute__((ext_vector_type(4))) float f32x4;

// ---------------- QKV GEMM: C = A @ B^T, fp32 vector, BK=16, padded LDS ----
__global__ __launch_bounds__(256)
void gemm_qkv(const float* __restrict__ A, const float* __restrict__ B,
              float* __restrict__ C)
{
    __shared__ __align__(16) float As[16][132];
    __shared__ __align__(16) float Bs[16][132];
    const int tid = threadIdx.x;
    const int tx = tid & 15, ty = tid >> 4;
    const int m0 = blockIdx.y * 128, n0 = blockIdx.x * 128;

    const int r  = tid >> 2;
    const int kc = (tid & 3) << 2;
    const float* ApL = A + (i64)(m0 + r)      * CH + kc;
    const float* ApH = A + (i64)(m0 + r + 64) * CH + kc;
    const float* BpL = B + (i64)(n0 + r)      * CH + kc;
    const float* BpH = B + (i64)(n0 + r + 64) * CH + kc;

    float4 a0 = *(const float4*)ApL, a1 = *(const float4*)ApH;
    float4 b0 = *(const float4*)BpL, b1 = *(const float4*)BpH;

    float acc[8][8];
#pragma unroll
    for (int i = 0; i < 8; i++)
#pragma unroll
        for (int j = 0; j < 8; j++) acc[i][j] = 0.0f;

    for (int k0 = 0; k0 < CH; k0 += 16) {
        __syncthreads();
#pragma unroll
        for (int j = 0; j < 4; j++) {
            As[kc+j][r]    = ((const float*)&a0)[j];
            As[kc+j][r+64] = ((const float*)&a1)[j];
            Bs[kc+j][r]    = ((const float*)&b0)[j];
            Bs[kc+j][r+64] = ((const float*)&b1)[j];
        }
        __syncthreads();
        if (k0 + 16 < CH) {
            a0 = *(const float4*)(ApL + k0 + 16);
            a1 = *(const float4*)(ApH + k0 + 16);
            b0 = *(const float4*)(BpL + k0 + 16);
            b1 = *(const float4*)(BpH + k0 + 16);
        }
#pragma unroll
        for (int kk = 0; kk < 16; kk++) {
            float4 x0 = *(const float4*)&As[kk][ty*4];
            float4 x1 = *(const float4*)&As[kk][64 + ty*4];
            float4 y0 = *(const float4*)&Bs[kk][tx*4];
            float4 y1 = *(const float4*)&Bs[kk][64 + tx*4];
            float a[8]  = {x0.x,x0.y,x0.z,x0.w,x1.x,x1.y,x1.z,x1.w};
            float bb[8] = {y0.x,y0.y,y0.z,y0.w,y1.x,y1.y,y1.z,y1.w};
#pragma unroll
            for (int i = 0; i < 8; i++)
#pragma unroll
                for (int j = 0; j < 8; j++)
                    acc[i][j] = fmaf(a[i], bb[j], acc[i][j]);
        }
    }

#pragma unroll
    for (int i = 0; i < 8; i++) {
        const int row = m0 + ty*4 + (i & 3) + ((i >> 2) * 64);
#pragma unroll
        for (int jg = 0; jg < 2; jg++) {
            const int col = n0 + jg*64 + tx*4;
            float4 o = make_float4(acc[i][jg*4+0], acc[i][jg*4+1],
                                   acc[i][jg*4+2], acc[i][jg*4+3]);
            *(float4*)&C[(i64)row * (3*CH) + col] = o;
        }
    }
}

// ---------------- scores GEMM: K=64 in two BK=32 phases (unchanged R5) -----
__global__ __launch_bounds__(256)
void gemm_scores(const float* __restrict__ qkv, float* __restrict__ scores,
                 int b_base, i64 sC)
{
    __shared__ __align__(16) float As[32][132];
    __shared__ __align__(16) float Bs[32][132];
    const int tid = threadIdx.x;
    const int tx = tid & 15, ty = tid >> 4;
    const int m0 = blockIdx.y * 128, n0 = blockIdx.x * 128;
    const int b = b_base + blockIdx.z / NH, h = blockIdx.z % NH;

    const float* A = qkv + (i64)b * SEQ * (3*CH) + h * DH;
    const float* B = A + CH;
    float* C = scores + (i64)blockIdx.z * sC;

    const int lrow = tid >> 2;
    const int lk4 = (tid & 3) * 4;
    const float* Aro[2];
    const float* Bro[2];
#pragma unroll
    for (int g = 0; g < 2; g++) {
        int ar = m0 + g*64 + lrow; if (ar > SEQ-1) ar = SEQ-1;
        int br = n0 + g*64 + lrow; if (br > SEQ-1) br = SEQ-1;
        Aro[g] = A + (i64)ar * (3*CH);
        Bro[g] = B + (i64)br * (3*CH);
    }

    float4 av[2][2], bv[2][2];
#pragma unroll
    for (int g = 0; g < 2; g++)
#pragma unroll
        for (int c = 0; c < 2; c++) {
            av[g][c] = *(const float4*)(Aro[g] + lk4 + c*16);
            bv[g][c] = *(const float4*)(Bro[g] + lk4 + c*16);
        }

    float acc[8][8];
#pragma unroll
    for (int i = 0; i < 8; i++)
#pragma unroll
        for (int j = 0; j < 8; j++) acc[i][j] = 0.0f;

#pragma unroll
    for (int ph = 0; ph < 2; ph++) {
        if (ph) __syncthreads();
#pragma unroll
        for (int g = 0; g < 2; g++)
#pragma unroll
            for (int c = 0; c < 2; c++)
#pragma unroll
                for (int j = 0; j < 4; j++) {
                    As[lk4 + c*16 + j][g*64 + lrow] = ((const float*)&av[g][c])[j];
                    Bs[lk4 + c*16 + j][g*64 + lrow] = ((const float*)&bv[g][c])[j];
                }
        __syncthreads();
        if (ph == 0) {
#pragma unroll
            for (int g = 0; g < 2; g++)
#pragma unroll
                for (int c = 0; c < 2; c++) {
                    av[g][c] = *(const float4*)(Aro[g] + 32 + lk4 + c*16);
                    bv[g][c] = *(const float4*)(Bro[g] + 32 + lk4 + c*16);
                }
        }
#pragma unroll 8
        for (int kk = 0; kk < 32; kk++) {
            float4 x0 = *(const float4*)&As[kk][ty*4];
            float4 x1 = *(const float4*)&As[kk][64 + ty*4];
            float4 y0 = *(const float4*)&Bs[kk][tx*4];
            float4 y1 = *(const float4*)&Bs[kk][64 + tx*4];
            float a[8]  = {x0.x,x0.y,x0.z,x0.w,x1.x,x1.y,x1.z,x1.w};
            float bb[8] = {y0.x,y0.y,y0.z,y0.w,y1.x,y1.y,y1.z,y1.w};
#pragma unroll
            for (int i = 0; i < 8; i++)
#pragma unroll
                for (int j = 0; j < 8; j++)
                    acc[i][j] = fmaf(a[i], bb[j], acc[i][j]);
        }
    }

#pragma unroll
    for (int i = 0; i < 8; i++) {
        const int row = m0 + ty*4 + (i & 3) + ((i >> 2) * 64);
        if (row >= SEQ) continue;
#pragma unroll
        for (int jg = 0; jg < 2; jg++) {
            const int col = n0 + jg*64 + tx*4;
            if (col >= SEQ) continue;
            float4 o = make_float4(0.125f*acc[i][jg*4+0], 0.125f*acc[i][jg*4+1],
                                   0.125f*acc[i][jg*4+2], 0.125f*acc[i][jg*4+3]);
            *(float4*)&C[(i64)row * SEQ + col] = o;
        }
    }
}

// ---------------- proj: bf16 MFMA (verified R3) ----------------------------
__global__ __launch_bounds__(256)
void gemm_proj(const unsigned short* __restrict__ Abf,
               const unsigned short* __restrict__ Bbf,
               const float* __restrict__ bias, float* __restrict__ C)
{
    __shared__ __align__(16) unsigned short As[128 * 40];
    __shared__ __align__(16) unsigned short Bs[128 * 40];
    const int tid = threadIdx.x;
    const int lane = tid & 63, w = tid >> 6;
    const int wm = (w >> 1) * 64, wn = (w & 1) * 64;
    const int m0 = blockIdx.y * 128, n0 = blockIdx.x * 128;

    f32x4 acc[4][4];
#pragma unroll
    for (int i = 0; i < 4; i++)
#pragma unroll
        for (int j = 0; j < 4; j++) acc[i][j] = (f32x4){0.f,0.f,0.f,0.f};

    const int q = lane >> 4;
    const int rA = lane & 15;

    for (int k0 = 0; k0 < CH; k0 += 32) {
        __syncthreads();
#pragma unroll
        for (int rep = 0; rep < 2; rep++) {
            const int id = rep * 256 + tid;
            const int row = id >> 2, c = id & 3;
            *(uint4*)&As[row*40 + c*8] = *(const uint4*)&Abf[(i64)(m0+row)*CH + k0 + c*8];
            *(uint4*)&Bs[row*40 + c*8] = *(const uint4*)&Bbf[(i64)(n0+row)*CH + k0 + c*8];
        }
        __syncthreads();
#pragma unroll
        for (int mt = 0; mt < 4; mt++) {
            bf16x8 a = *(const bf16x8*)&As[(wm + mt*16 + rA)*40 + q*8];
#pragma unroll
            for (int nt = 0; nt < 4; nt++) {
                bf16x8 b = *(const bf16x8*)&Bs[(wn + nt*16 + rA)*40 + q*8];
                acc[mt][nt] = __builtin_amdgcn_mfma_f32_16x16x32_bf16(a, b, acc[mt][nt], 0, 0, 0);
            }
        }
    }

#pragma unroll
    for (int mt = 0; mt < 4; mt++)
#pragma unroll
        for (int nt = 0; nt < 4; nt++) {
            const int col = n0 + wn + nt*16 + (lane & 15);
            const float bcol = bias[col];
#pragma unroll
            for (int rg = 0; rg < 4; rg++) {
                const int row = m0 + wm + mt*16 + (lane >> 4)*4 + rg;
                C[(i64)row * CH + col] = acc[mt][nt][rg] + bcol;
            }
        }
}

__global__ __launch_bounds__(256)
void cast_w(const float* __restrict__ src, unsigned short* __restrict__ dst, int n4)
{
    int i = blockIdx.x * 256 + threadIdx.x;
    if (i >= n4) return;
    float4 v = *(const float4*)&src[i*4];
    unsigned short o[4];
    o[0] = __bfloat16_as_ushort(__float2bfloat16(v.x));
    o[1] = __bfloat16_as_ushort(__float2bfloat16(v.y));
    o[2] = __bfloat16_as_ushort(__float2bfloat16(v.z));
    o[3] = __bfloat16_as_ushort(__float2bfloat16(v.w));
    *(uint2*)&dst[i*4] = *(uint2*)o;
}

// ---------------- top-k select: ONE WAVE PER ROW, zero barriers ------------
// Lane l owns elements m = l + 64*j, j=0..12 (slot 12 valid for l<16).
// Threshold via per-bit binary search on the orderable key (wave-reduce count),
// early exit when count(>=cand)==K. Compaction via ballot prefix into a tiny
// LDS list; gather is a fixed 100-iteration coalesced loop.
__device__ __forceinline__ int wave_isum(int v) {
#pragma unroll
    for (int m = 32; m; m >>= 1) v += __shfl_xor(v, m, 64);
    return v;
}
__device__ __forceinline__ float wave_fsum(float v) {
#pragma unroll
    for (int m = 32; m; m >>= 1) v += __shfl_xor(v, m, 64);
    return v;
}
__device__ __forceinline__ unsigned fkey(float t) {
    unsigned bits = __float_as_uint(t);
    return (bits & 0x80000000u) ? ~bits : (bits | 0x80000000u);
}

__global__ __launch_bounds__(64)
void select_topk(const float* __restrict__ scores, i64 sstride,
                 const float* __restrict__ ucb_cnt,
                 const float* __restrict__ qkv,
                 unsigned short* __restrict__ ctxbf,
                 float* __restrict__ sdelta,
                 const int* __restrict__ counter_p,
                 int b0, int b1)
{
    __shared__ uint2 list[K_TOP];   // (.x = weight bits, .y = index)

    const int lane = threadIdx.x;
    const int n = blockIdx.x, h = blockIdx.y;
    const float L = logf((float)(*counter_p));
    const i64 rowoff = ((i64)h * SEQ + n) * SEQ;
    const unsigned long long lt = (1ull << lane) - 1ull;
    const bool last_ok = lane < (SEQ - 64*(NSLOT-1));   // slot-12 validity

    // ucb bonus (shared across b): 13 regs
    float bon[NSLOT];
#pragma unroll
    for (int j = 0; j < NSLOT; j++) {
        float c = (j < NSLOT-1 || last_ok) ? ucb_cnt[rowoff + j*64 + lane] : 1.0f;
        bon[j] = sqrtf(L / (c + 1e-6f));
    }
    int cnt_acc[NSLOT];
#pragma unroll
    for (int j = 0; j < NSLOT; j++) cnt_acc[j] = 0;

    for (int b = b0; b < b1; b++) {
        const float* srow = scores + (i64)(b - b0) * sstride + rowoff;
        float s[NSLOT];
        unsigned uv[NSLOT];
#pragma unroll
        for (int j = 0; j < NSLOT; j++) {
            const bool v = (j < NSLOT-1 || last_ok);
            s[j]  = v ? srow[j*64 + lane] : 0.0f;
            uv[j] = v ? fkey(s[j] + bon[j]) : 0u;   // key 0 < any real key
        }

        // ---- binary-search the K-th largest key ----
        unsigned prefix = 0u;
        bool exact = false;
        for (int bit = 31; bit >= 0; bit--) {
            const unsigned cand = prefix | (1u << bit);
            int c = 0;
#pragma unroll
            for (int j = 0; j < NSLOT; j++) c += (uv[j] >= cand);
            c = wave_isum(c);
            if (c >= K_TOP) {
                prefix = cand;
                if (c == K_TOP) { exact = true; break; }
            }
        }
        const unsigned T = prefix;

        // ---- selection flags (registers only) ----
        int sel[NSLOT];
        if (exact) {
#pragma unroll
            for (int j = 0; j < NSLOT; j++) sel[j] = (uv[j] >= T);
        } else {
            int cg = 0;
#pragma unroll
            for (int j = 0; j < NSLOT; j++) { sel[j] = (uv[j] > T); cg += sel[j]; }
            int rfin = K_TOP - wave_isum(cg);   // how many ==T to take, by index
            // index order = slot-major (m = j*64 + lane): walk slots, lane-order
#pragma unroll
            for (int j = 0; j < NSLOT; j++) {
                const bool eq = (uv[j] == T);
                unsigned long long m = __ballot(eq);
                const int cnt = (int)__popcll(m);
                const int take = cnt < rfin ? cnt : rfin;
                if (eq && (int)__popcll(m & lt) < take) sel[j] = 1;
                rfin -= take;
            }
        }

        // ---- weight sum + per-element count accum ----
        float pw = 0.f;
#pragma unroll
        for (int j = 0; j < NSLOT; j++) {
            if (sel[j]) { pw += s[j]; cnt_acc[j]++; }
        }
        const float inv = 1.0f / (wave_fsum(pw) + 1e-8f);

        // ---- compact (idx, weight) into LDS list via ballot prefix ----
        int base = 0;
#pragma unroll
        for (int j = 0; j < NSLOT; j++) {
            unsigned long long m = __ballot(sel[j] != 0);
            if (sel[j]) {
                const int pos = base + (int)__popcll(m & lt);
                list[pos] = make_uint2(__float_as_uint(s[j]), (unsigned)(j*64 + lane));
            }
            base += (int)__popcll(m);
        }
        __syncthreads();   // single-wave: compiles to a cheap waitcnt fence

        // ---- gather: acc_d = sum_j w_j * v[idx_j][d], d = lane ----
        const float* vb = qkv + (i64)b * SEQ * (3*CH) + 2*CH + h * DH + lane;
        float acc = 0.f;
#pragma unroll 4
        for (int j = 0; j < K_TOP; j++) {
            uint2 e = list[j];
            acc = fmaf(__uint_as_float(e.x), vb[(i64)e.y * (3*CH)], acc);
        }
        ctxbf[((i64)b * SEQ + n) * CH + h * DH + lane] =
            __bfloat16_as_ushort(__float2bfloat16(inv * acc));
        __syncthreads();   // list reused next b
    }

    // ---- score_delta ----
#pragma unroll
    for (int j = 0; j < NSLOT; j++) {
        if (j < NSLOT-1 || last_ok) {
            float o = (float)cnt_acc[j];
            float* dst = &sdelta[rowoff + j*64 + lane];
            if (b0 != 0) o += *dst;
            *dst = o;
        }
    }
}

extern "C" void kernel_launch(void* const* d_in, const int* in_sizes, int n_in,
                              void* d_out, int out_size, void* d_ws, size_t ws_size,
                              hipStream_t stream) {
    const float* x      = (const float*)d_in[0];
    const float* ucb    = (const float*)d_in[1];
    const float* qkv_w  = (const float*)d_in[2];
    const float* proj_w = (const float*)d_in[3];
    const float* proj_b = (const float*)d_in[4];
    const int*   counter = (const int*)d_in[5];

    float* out0   = (float*)d_out;
    float* sdelta = out0 + (i64)NB * SEQ * CH;

    const size_t qkv_f  = (size_t)NB * SEQ * (3*CH);
    const size_t ctx_h  = (size_t)NB * SEQ * CH;
    const size_t w_h    = (size_t)CH * CH;

    float* qkv_buf = (float*)d_ws;
    unsigned short* ctx_bf = (unsigned short*)(qkv_buf + qkv_f);
    unsigned short* w_bf   = ctx_bf + ctx_h;
    size_t off = ((qkv_f * 4 + (ctx_h + w_h) * 2) + 15) & ~(size_t)15;
    float* scores = (float*)((char*)d_ws + off);

    const size_t per_b = (size_t)NH * SEQ * SEQ * 4;
    int nbc = (ws_size > off) ? (int)((ws_size - off) / per_b) : 1;
    if (nbc < 1) nbc = 1;
    if (nbc > NB) nbc = NB;

    dim3 blk(256);

    cast_w<<<dim3((CH*CH/4 + 255)/256), blk, 0, stream>>>(proj_w, w_bf, CH*CH/4);
    gemm_qkv<<<dim3(18, 49), blk, 0, stream>>>(x, qkv_w, qkv_buf);

    for (int b0 = 0; b0 < NB; b0 += nbc) {
        const int bn = (b0 + nbc <= NB) ? nbc : (NB - b0);
        gemm_scores<<<dim3(7, 7, bn*NH), blk, 0, stream>>>(
            qkv_buf, scores, b0, (i64)SEQ*SEQ);
        select_topk<<<dim3(SEQ, NH), dim3(64), 0, stream>>>(
            scores, (i64)NH*SEQ*SEQ, ucb, qkv_buf, ctx_bf, sdelta, counter,
            b0, b0 + bn);
    }

    gemm_proj<<<dim3(6, 49), blk, 0, stream>>>(ctx_bf, w_bf, proj_b, out0);
}